// Round 17
// baseline (182.952 us; speedup 1.0000x reference)
//
#include <hip/hip_runtime.h>
#include <hip/hip_bf16.h>

// out[n] = b + e_x[n] * sum_m exp(2*GAMMA*dot(x_n,y_m)) * c[m]
// n=16384, m=8192, d=512.
// Round 17: r12 structure with 32x32x16 MFMA (was 16x16x32). Same traffic,
// HALF the MFMA instructions per chunk (4 vs 8), 17% faster matrix pipe
// (2382 vs 2075 TF ubench). A LDS blocks now [q16][sub4] of 32row x 16k
// (read = base + lane*16, conflict-free); B frag layout re-laid for 32x32
// (lane: col=lane&31, khalf=lane>>5). C/D map (HW-verified m74/m101):
// col=lane&31, row=(r&3)+8*(r>>2)+4*(lane>>5).
//
// Workspace: Xb bf16[16384*512] @0, Ybt bf16[8192*512] @16777216 (frag layout),
//            ex f32[16384] @25165824, cw f32[8192] @25231360.

#define GAMMA 0.002f

typedef __bf16 bf16x8 __attribute__((ext_vector_type(8)));
typedef float  f32x16 __attribute__((ext_vector_type(16)));
typedef __attribute__((address_space(3))) void lds_void_t;
typedef __attribute__((address_space(1))) const void gl_void_t;

// ---------------- prep X: f32 -> bf16 row-major + ex = exp(-g*||x||^2)
__global__ __launch_bounds__(256) void prep_x(const float* __restrict__ src,
                                              __bf16* __restrict__ dst,
                                              float* __restrict__ fac) {
    const int wid  = threadIdx.x >> 6;
    const int lane = threadIdx.x & 63;
    const int row  = blockIdx.x * 4 + wid;
    const float4* s = reinterpret_cast<const float4*>(src + (size_t)row * 512);
    float4 v0 = s[lane * 2];
    float4 v1 = s[lane * 2 + 1];
    float acc = v0.x * v0.x + v0.y * v0.y + v0.z * v0.z + v0.w * v0.w
              + v1.x * v1.x + v1.y * v1.y + v1.z * v1.z + v1.w * v1.w;
    bf16x8 o;
    o[0] = (__bf16)v0.x; o[1] = (__bf16)v0.y; o[2] = (__bf16)v0.z; o[3] = (__bf16)v0.w;
    o[4] = (__bf16)v1.x; o[5] = (__bf16)v1.y; o[6] = (__bf16)v1.z; o[7] = (__bf16)v1.w;
    *reinterpret_cast<bf16x8*>(dst + (size_t)row * 512 + lane * 8) = o;
#pragma unroll
    for (int off = 32; off >= 1; off >>= 1) acc += __shfl_xor(acc, off, 64);
    if (lane == 0) fac[row] = __expf(-GAMMA * acc);
}

// ---------------- prep Y: f32 -> bf16 32x32-FRAGMENT layout + cw
// B-frag for 32x32x16: lane holds col=lane&31, k = (lane>>5)*8 + [0..7].
// Block (cb = m>>5, kb = k>>4) of 1KB: granule = ((k>>3)&1)*32 + (m&31).
// Elem idx = ((size_t)cb*32 + kb)*512 + granule*8 + (k&7).
// prep lane covers k = lane*8..+7 -> kb = lane>>1, khalf = lane&1.
__global__ __launch_bounds__(256) void prep_y(const float* __restrict__ src,
                                              __bf16* __restrict__ dst,
                                              float* __restrict__ fac,
                                              const float* __restrict__ W) {
    const int wid  = threadIdx.x >> 6;
    const int lane = threadIdx.x & 63;
    const int m    = blockIdx.x * 4 + wid;
    const float4* s = reinterpret_cast<const float4*>(src + (size_t)m * 512);
    float4 v0 = s[lane * 2];
    float4 v1 = s[lane * 2 + 1];
    float acc = v0.x * v0.x + v0.y * v0.y + v0.z * v0.z + v0.w * v0.w
              + v1.x * v1.x + v1.y * v1.y + v1.z * v1.z + v1.w * v1.w;
    bf16x8 o;
    o[0] = (__bf16)v0.x; o[1] = (__bf16)v0.y; o[2] = (__bf16)v0.z; o[3] = (__bf16)v0.w;
    o[4] = (__bf16)v1.x; o[5] = (__bf16)v1.y; o[6] = (__bf16)v1.z; o[7] = (__bf16)v1.w;
    const size_t idx = ((size_t)(m >> 5) * 32 + (lane >> 1)) * 512
                     + ((lane & 1) * 32 + (m & 31)) * 8;
    *reinterpret_cast<bf16x8*>(dst + idx) = o;
#pragma unroll
    for (int off = 32; off >= 1; off >>= 1) acc += __shfl_xor(acc, off, 64);
    if (lane == 0) fac[m] = __expf(-GAMMA * acc) * W[m];
}

__global__ void init_out(float* __restrict__ out, const float* __restrict__ b, int n) {
    int i = blockIdx.x * blockDim.x + threadIdx.x;
    if (i < n) out[i] = b[0];
}

// ---------------- LDS (80KB/block): A @0: [q 16][sub 4][1KB]; sub = ks*2+rt
// = (k-half of 32-chunk)*2 + rowtile. Each 1KB = 32 rows x 16 k in 32x32x16
// A-frag order (granule = khalf*32 + row) -> read = base + lane*16.
// cw @65536: 16KB (block's col-half).

// chunk C 0..255: q = C&15 (k = q*32), panel p = C>>4; wave owns colblock32
// cbg32 + p*8 (32 cols). kb = 2q, 2q+1 adjacent in Ybt (+1024B).
#define LOADB(B, C) do { \
    const int q_ = (C) & 15, p_ = (C) >> 4; \
    const __bf16* bp_ = Ybt + ((size_t)(cbg32 + p_ * 8) * 32 + 2 * q_) * 512 + lane8; \
    B[0] = *reinterpret_cast<const bf16x8*>(bp_); \
    B[1] = *reinterpret_cast<const bf16x8*>(bp_ + 512); \
} while (0)

#define READA(AF, Q) do { \
    _Pragma("unroll") \
    for (int j = 0; j < 4; ++j) \
        AF[j] = *reinterpret_cast<const bf16x8*>( \
            &smem[(Q) * 4096 + j * 1024 + lane16]); \
} while (0)

// 4 MFMA 32x32x16: af[ks*2+rt] x B[ks] -> acc[rt]
#define MFMA4(AF, B) do { \
    __builtin_amdgcn_s_setprio(1); \
    acc[0] = __builtin_amdgcn_mfma_f32_32x32x16_bf16(AF[0], B[0], acc[0], 0, 0, 0); \
    acc[1] = __builtin_amdgcn_mfma_f32_32x32x16_bf16(AF[1], B[0], acc[1], 0, 0, 0); \
    acc[0] = __builtin_amdgcn_mfma_f32_32x32x16_bf16(AF[2], B[1], acc[0], 0, 0, 0); \
    acc[1] = __builtin_amdgcn_mfma_f32_32x32x16_bf16(AF[3], B[1], acc[1], 0, 0, 0); \
    __builtin_amdgcn_s_setprio(0); \
} while (0)

// grid: 512 blocks (2/CU), 512 threads (8 waves; wave tile 64 rows x 32 cols)
__global__ __launch_bounds__(512, 4) void rbf_gemm(
    const __bf16* __restrict__ Xb, const __bf16* __restrict__ Ybt,
    const float* __restrict__ ex, const float* __restrict__ cwp,
    float* __restrict__ out) {
    __shared__ __align__(128) char smem[81920];

    const int tid  = threadIdx.x;
    const int wid  = tid >> 6;
    const int lane = tid & 63;

    // XCD map (r9-proven): even XCDs -> col-half 0, odd -> 1; 64 blocks/XCD
    // share one 4MB Ybt half (L2-fit). rg = 64-row group.
    const int pid = blockIdx.x;
    const int xcd = pid & 7;
    const int j   = pid >> 3;                    // 0..63
    const int ch  = xcd & 1;
    const int rg  = (xcd >> 1) * 64 + j;         // 0..255
    const int rowBase = rg * 64;
    const int cbg32   = ch * 128 + wid;          // wave's 32-colblock base

    const int l31 = lane & 31, lhi = lane >> 5;
    const int lane16 = lane * 16;
    const int lane8  = lane * 8;

    // ---- prologue: A panel (64 x 1KB 32x32-frag blocks, gather src) + cw
#pragma unroll
    for (int i = 0; i < 8; ++i) {
        const int blk = wid * 8 + i;
        const int q = blk >> 2, sub = blk & 3;
        const int ksp = sub >> 1, rt = sub & 1;
        const __bf16* src = Xb + (size_t)(rowBase + rt * 32 + l31) * 512
                          + q * 32 + ksp * 16 + lhi * 8;
        __builtin_amdgcn_global_load_lds((gl_void_t*)src,
            (lds_void_t*)(smem + blk * 1024), 16, 0, 0);
    }
#pragma unroll
    for (int i = 0; i < 2; ++i)
        __builtin_amdgcn_global_load_lds(
            (gl_void_t*)(cwp + ch * 4096 + wid * 512 + i * 256 + lane * 4),
            (lds_void_t*)(smem + 65536 + wid * 2048 + i * 1024), 16, 0, 0);
    asm volatile("s_waitcnt vmcnt(0)");
    __builtin_amdgcn_s_barrier();        // the only barrier; LDS read-only after

    f32x16 acc[2] = {};
    float rowsum[2][16] = {};

    bf16x8 AF[4], B0[2], B1[2];
    LOADB(B0, 0);

    // ---- main: 256 chunks (16 panels x 16 kchunks), no barriers, reg dbuf.
    for (int cc = 0; cc < 128; ++cc) {
        const int ce = 2 * cc, co = 2 * cc + 1;
        LOADB(B1, co);
        READA(AF, ce & 15);
        MFMA4(AF, B0);
        LOADB(B0, (co + 1) & 255);
        READA(AF, co & 15);
        MFMA4(AF, B1);
        if ((cc & 7) == 7) {
            // ---- per-panel epilogue: acc holds full K=512 for 64r x 32c.
            const int p = cc >> 3;
            const float cv = *reinterpret_cast<const float*>(
                &smem[65536 + ((p * 8 + wid) * 32 + l31) * 4]);
#pragma unroll
            for (int rt = 0; rt < 2; ++rt)
#pragma unroll
                for (int r = 0; r < 16; ++r)
                    rowsum[rt][r] += __expf(0.004f * acc[rt][r]) * cv;
            acc[0] = f32x16{};
            acc[1] = f32x16{};
        }
    }

    // ---- final: reduce across the 32 cols (lanes within each half) + atomic
#pragma unroll
    for (int rt = 0; rt < 2; ++rt)
#pragma unroll
        for (int r = 0; r < 16; ++r) {
            float s = rowsum[rt][r];
#pragma unroll
            for (int off = 1; off < 32; off <<= 1) s += __shfl_xor(s, off, 64);
            if (l31 == 0) {
                const int n = rowBase + rt * 32 + (r & 3) + 8 * (r >> 2) + 4 * lhi;
                atomicAdd(&out[n], ex[n] * s);
            }
        }
}

extern "C" void kernel_launch(void* const* d_in, const int* in_sizes, int n_in,
                              void* d_out, int out_size, void* d_ws, size_t ws_size,
                              hipStream_t stream) {
    const float* X = (const float*)d_in[0];   // 16384 x 512
    const float* Y = (const float*)d_in[1];   //  8192 x 512
    const float* W = (const float*)d_in[2];   // 8192
    const float* b = (const float*)d_in[3];   // 1
    float* out = (float*)d_out;               // 16384

    char* ws = (char*)d_ws;
    __bf16* Xb  = (__bf16*)(ws);
    __bf16* Ybt = (__bf16*)(ws + 16777216);
    float*  ex  = (float*)(ws + 16777216 + 8388608);
    float*  cw  = (float*)(ws + 16777216 + 8388608 + 65536);

    prep_x<<<4096, 256, 0, stream>>>(X, Xb, ex);
    prep_y<<<2048, 256, 0, stream>>>(Y, Ybt, cw, W);
    init_out<<<64, 256, 0, stream>>>(out, b, 16384);
    rbf_gemm<<<512, 512, 0, stream>>>(Xb, Ybt, ex, cw, out);
}

// Round 18
// 145.364 us; speedup vs baseline: 1.2586x; 1.2586x over previous
//
#include <hip/hip_runtime.h>
#include <hip/hip_bf16.h>

// out[n] = b + e_x[n] * sum_m exp(2*GAMMA*dot(x_n,y_m)) * c[m]
// n=16384, m=8192, d=512.
// Round 18: LDS-traffic-halving 64x64 wave tile, register-balanced.
// Diagnosis (r9-r17): per chunk-step per CU, LDS ds_read demand (768cyc) >
// MFMA (621) > VALU -- LDS redundancy (8 waves re-read the same A frags) is
// the binding pipe. 64x64 tile halves A-reads AND VALU per MFMA -> MFMA pipe
// becomes the wall. Budget fix vs failed r10/r11: SINGLE A + SINGLE B frag
// sets (pinning proven null 3x, compiler renames anyway), rowsum in regs,
// end-only reduce+atomic. 64+16+16+16 ~= 112 regs < 128 -> no spill.
// init_out folded into prep_x.
//
// Workspace: Xb bf16[16384*512] @0, Ybt bf16[8192*512] @16777216 (frag layout),
//            ex f32[16384] @25165824, cw f32[8192] @25231360.

#define GAMMA 0.002f

typedef __bf16 bf16x8 __attribute__((ext_vector_type(8)));
typedef float  f32x4  __attribute__((ext_vector_type(4)));
typedef __attribute__((address_space(3))) void lds_void_t;
typedef __attribute__((address_space(1))) const void gl_void_t;

// ---------------- prep X: f32 -> bf16 row-major + ex = exp(-g*||x||^2)
//                  + out[row] = b[0]  (init_out folded in)
__global__ __launch_bounds__(256) void prep_x(const float* __restrict__ src,
                                              __bf16* __restrict__ dst,
                                              float* __restrict__ fac,
                                              float* __restrict__ out,
                                              const float* __restrict__ bias) {
    const int wid  = threadIdx.x >> 6;
    const int lane = threadIdx.x & 63;
    const int row  = blockIdx.x * 4 + wid;
    const float4* s = reinterpret_cast<const float4*>(src + (size_t)row * 512);
    float4 v0 = s[lane * 2];
    float4 v1 = s[lane * 2 + 1];
    float acc = v0.x * v0.x + v0.y * v0.y + v0.z * v0.z + v0.w * v0.w
              + v1.x * v1.x + v1.y * v1.y + v1.z * v1.z + v1.w * v1.w;
    bf16x8 o;
    o[0] = (__bf16)v0.x; o[1] = (__bf16)v0.y; o[2] = (__bf16)v0.z; o[3] = (__bf16)v0.w;
    o[4] = (__bf16)v1.x; o[5] = (__bf16)v1.y; o[6] = (__bf16)v1.z; o[7] = (__bf16)v1.w;
    *reinterpret_cast<bf16x8*>(dst + (size_t)row * 512 + lane * 8) = o;
#pragma unroll
    for (int off = 32; off >= 1; off >>= 1) acc += __shfl_xor(acc, off, 64);
    if (lane == 0) {
        fac[row] = __expf(-GAMMA * acc);
        out[row] = bias[0];
    }
}

// ---------------- prep Y: f32 -> bf16 FRAGMENT layout + cw = exp(-g*||y||^2)*W
// Ybt elem index for (m,k): q=k>>5, cb=m>>4, kslot=(k>>3)&3, col'=m&15:
//   ((q*512 + cb)*512) + (kslot*16 + col')*8 + (k&7)
// -> B-frag (q,cb) read = base + lane*8 elems (contiguous 1KB/wave).
__global__ __launch_bounds__(256) void prep_y(const float* __restrict__ src,
                                              __bf16* __restrict__ dst,
                                              float* __restrict__ fac,
                                              const float* __restrict__ W) {
    const int wid  = threadIdx.x >> 6;
    const int lane = threadIdx.x & 63;
    const int m    = blockIdx.x * 4 + wid;
    const float4* s = reinterpret_cast<const float4*>(src + (size_t)m * 512);
    float4 v0 = s[lane * 2];
    float4 v1 = s[lane * 2 + 1];
    float acc = v0.x * v0.x + v0.y * v0.y + v0.z * v0.z + v0.w * v0.w
              + v1.x * v1.x + v1.y * v1.y + v1.z * v1.z + v1.w * v1.w;
    bf16x8 o;
    o[0] = (__bf16)v0.x; o[1] = (__bf16)v0.y; o[2] = (__bf16)v0.z; o[3] = (__bf16)v0.w;
    o[4] = (__bf16)v1.x; o[5] = (__bf16)v1.y; o[6] = (__bf16)v1.z; o[7] = (__bf16)v1.w;
    const size_t idx = ((size_t)(lane >> 2) * 512 + (m >> 4)) * 512
                     + ((lane & 3) * 16 + (m & 15)) * 8;
    *reinterpret_cast<bf16x8*>(dst + idx) = o;
#pragma unroll
    for (int off = 32; off >= 1; off >>= 1) acc += __shfl_xor(acc, off, 64);
    if (lane == 0) fac[m] = __expf(-GAMMA * acc) * W[m];
}

// ---------------- LDS (80KB/block): A @0: [q 16][rb 4][1KB] k-major frag
// blocks (lane*16 read, conflict-free); cw @65536: 16KB (block's col-half).

// chunk C 0..127: q = C&15, panel p = C>>4 (8 panels x 512 cols).
// Wave owns colblocks cbgBase + p*32 .. +3 (64 cols of the panel).
#define LOADB(B, C) do { \
    const int q_ = (C) & 15, p_ = (C) >> 4; \
    const __bf16* bp_ = Ybt + ((size_t)q_ * 512 + cbgBase + p_ * 32) * 512 + lane8; \
    B[0] = *reinterpret_cast<const bf16x8*>(bp_); \
    B[1] = *reinterpret_cast<const bf16x8*>(bp_ + 512); \
    B[2] = *reinterpret_cast<const bf16x8*>(bp_ + 1024); \
    B[3] = *reinterpret_cast<const bf16x8*>(bp_ + 1536); \
} while (0)

#define READA(A, Q) do { \
    _Pragma("unroll") \
    for (int rb = 0; rb < 4; ++rb) \
        A[rb] = *reinterpret_cast<const bf16x8*>( \
            &smem[(Q) * 4096 + rb * 1024 + lane16]); \
} while (0)

#define MFMA16(A, B) do { \
    __builtin_amdgcn_s_setprio(1); \
    _Pragma("unroll") \
    for (int rb = 0; rb < 4; ++rb) \
        _Pragma("unroll") \
        for (int cb = 0; cb < 4; ++cb) \
            acc[rb][cb] = __builtin_amdgcn_mfma_f32_16x16x32_bf16( \
                A[rb], B[cb], acc[rb][cb], 0, 0, 0); \
    __builtin_amdgcn_s_setprio(0); \
} while (0)

// grid: 512 blocks (2/CU), 512 threads (8 waves; wave tile 64 rows x 64 cols)
__global__ __launch_bounds__(512, 4) void rbf_gemm(
    const __bf16* __restrict__ Xb, const __bf16* __restrict__ Ybt,
    const float* __restrict__ ex, const float* __restrict__ cwp,
    float* __restrict__ out) {
    __shared__ __align__(128) char smem[81920];

    const int tid  = threadIdx.x;
    const int wid  = tid >> 6;
    const int lane = tid & 63;

    // XCD map (r9-proven): even XCDs -> col-half 0, odd -> 1; 64 blocks/XCD
    // share one 4MB Ybt half (L2-fit). rg = 64-row group.
    const int pid = blockIdx.x;
    const int xcd = pid & 7;
    const int j   = pid >> 3;                    // 0..63
    const int ch  = xcd & 1;
    const int rg  = (xcd >> 1) * 64 + j;         // 0..255
    const int rowBase = rg * 64;
    const int colBase = ch * 4096;
    const int cbgBase = ch * 256 + wid * 4;      // wave's colblock base per panel

    const int l15 = lane & 15, l4 = lane >> 4;
    const int lane16 = lane * 16;
    const int lane8  = lane * 8;

    // ---- prologue: A panel (64 x 1KB frag blocks, gather src) + cw -> LDS
#pragma unroll
    for (int i = 0; i < 8; ++i) {
        const int blk = wid * 8 + i;
        const int q = blk >> 2, rb = blk & 3;
        const __bf16* src = Xb + (size_t)(rowBase + rb * 16 + l15) * 512 + q * 32 + l4 * 8;
        __builtin_amdgcn_global_load_lds((gl_void_t*)src,
            (lds_void_t*)(smem + q * 4096 + rb * 1024), 16, 0, 0);
    }
#pragma unroll
    for (int i = 0; i < 2; ++i)
        __builtin_amdgcn_global_load_lds(
            (gl_void_t*)(cwp + colBase + wid * 512 + i * 256 + lane * 4),
            (lds_void_t*)(smem + 65536 + wid * 2048 + i * 1024), 16, 0, 0);
    asm volatile("s_waitcnt vmcnt(0)");
    __builtin_amdgcn_s_barrier();        // the only barrier; LDS read-only after

    f32x4 acc[4][4] = {};
    float rowsum[4][4] = {};

    bf16x8 A[4], B[4];

    // ---- main: 128 chunks (8 panels x 16 kchunks), single-buffered frags
    // (compiler renames/reorders freely -- pinning measured null 3x),
    // no barriers.
    for (int c = 0; c < 128; ++c) {
        LOADB(B, c);
        READA(A, c & 15);
        MFMA16(A, B);
        if ((c & 15) == 15) {
            // ---- per-panel epilogue: acc holds full K=512; pure VALU + LDS cw
            const int p = c >> 4;
            float cv[4];
#pragma unroll
            for (int cb = 0; cb < 4; ++cb)
                cv[cb] = *reinterpret_cast<const float*>(
                    &smem[65536 + (p * 512 + wid * 64 + cb * 16 + l15) * 4]);
#pragma unroll
            for (int rb = 0; rb < 4; ++rb)
#pragma unroll
                for (int i2 = 0; i2 < 4; ++i2) {
                    float s = rowsum[rb][i2];
#pragma unroll
                    for (int cb = 0; cb < 4; ++cb)
                        s += __expf(0.004f * acc[rb][cb][i2]) * cv[cb];
                    rowsum[rb][i2] = s;
                }
#pragma unroll
            for (int rb = 0; rb < 4; ++rb)
#pragma unroll
                for (int cb = 0; cb < 4; ++cb)
                    acc[rb][cb] = (f32x4){0.f, 0.f, 0.f, 0.f};
        }
    }

    // ---- final: 16-lane reduce + one atomic per (wave, n); out pre-init'd to b
#pragma unroll
    for (int rb = 0; rb < 4; ++rb)
#pragma unroll
        for (int i2 = 0; i2 < 4; ++i2) {
            float s = rowsum[rb][i2];
#pragma unroll
            for (int off = 1; off < 16; off <<= 1) s += __shfl_xor(s, off, 64);
            if (l15 == 0) {
                const int n = rowBase + rb * 16 + l4 * 4 + i2;
                atomicAdd(&out[n], ex[n] * s);
            }
        }
}

extern "C" void kernel_launch(void* const* d_in, const int* in_sizes, int n_in,
                              void* d_out, int out_size, void* d_ws, size_t ws_size,
                              hipStream_t stream) {
    const float* X = (const float*)d_in[0];   // 16384 x 512
    const float* Y = (const float*)d_in[1];   //  8192 x 512
    const float* W = (const float*)d_in[2];   // 8192
    const float* b = (const float*)d_in[3];   // 1
    float* out = (float*)d_out;               // 16384

    char* ws = (char*)d_ws;
    __bf16* Xb  = (__bf16*)(ws);
    __bf16* Ybt = (__bf16*)(ws + 16777216);
    float*  ex  = (float*)(ws + 16777216 + 8388608);
    float*  cw  = (float*)(ws + 16777216 + 8388608 + 65536);

    prep_x<<<4096, 256, 0, stream>>>(X, Xb, ex, out, b);
    prep_y<<<2048, 256, 0, stream>>>(Y, Ybt, cw, W);
    rbf_gemm<<<512, 512, 0, stream>>>(Xb, Ybt, ex, cw, out);
}